// Round 3
// baseline (520.319 us; speedup 1.0000x reference)
//
#include <hip/hip_runtime.h>

// ---------------------------------------------------------------------------
// CrossModalityCrossAttention on MI355X (gfx950). I/O: float32. Internal: bf16.
// B=4 S=4097 L=8065 D=1024 H=8 DH=64 CHUNK=64 CCS=128 n=64 chunks.
// Pipeline: transpose_w -> gemm<0> (Q) -> gemm<1> (KV) -> attn -> zero_rows
//           -> gemm<2> (out proj, f32 out).
// Workspace layout (bytes), total 100 MB:
//   qws   @ 0          : [b][h][n][64][64]  bf16  (16 MB)   q * 0.125
//   kws   @ 16777216   : [b][h][n][128][64] bf16  (32 MB)
//   vws   @ 50331648   : [b][h][n][128][64] bf16  (32 MB)
//   ows   @ 83886080   : [16384][512]       bf16  (16 MB)   attention output
//   wqT   @ 100663296  : [512][1024]  bf16 (Wq^T)
//   wkvT  @ 101711872  : [1024][1024] bf16 (Wkv^T)
//   woutT @ 103809024  : [1024][512]  bf16 (Wout^T)
// ---------------------------------------------------------------------------

typedef __attribute__((ext_vector_type(8))) short bf16x8;
typedef __attribute__((ext_vector_type(4))) float f32x4;

__device__ __forceinline__ short f2bf(float x) {        // RNE (epilogues, weights)
  union { float f; unsigned u; } v; v.f = x;
  unsigned r = v.u + 0x7FFFu + ((v.u >> 16) & 1u);
  return (short)(r >> 16);
}
__device__ __forceinline__ short f2bf_r(float x) {      // round-half-up (staging, 2 ops)
  union { float f; unsigned u; } v; v.f = x;
  return (short)((v.u + 0x8000u) >> 16);
}
__device__ __forceinline__ float bf2f(short s) {
  union { unsigned u; float f; } v;
  v.u = ((unsigned)(unsigned short)s) << 16;
  return v.f;
}

// ---------------- weight transpose (f32 [k][n] -> bf16 [n][k]) --------------
__global__ void transpose_w(const float* __restrict__ Wq, const float* __restrict__ Wkv,
                            const float* __restrict__ Wout,
                            short* __restrict__ wqT, short* __restrict__ wkvT,
                            short* __restrict__ woutT) {
  int idx = blockIdx.x * 256 + threadIdx.x;
  if (idx < 524288) {                       // Wq (1024 x 512)
    int d = idx >> 9, e = idx & 511;
    wqT[e * 1024 + d] = f2bf(Wq[idx]);
  } else if (idx < 1572864) {               // Wkv (1024 x 1024)
    int i = idx - 524288;
    int d = i >> 10, e = i & 1023;
    wkvT[e * 1024 + d] = f2bf(Wkv[i]);
  } else if (idx < 2097152) {               // Wout (512 x 1024)
    int i = idx - 1572864;
    int k = i >> 10, e = i & 1023;
    woutT[e * 512 + k] = f2bf(Wout[i]);
  }
}

// ---------------- zero the (b, 0, :) output rows (f32) ----------------------
__global__ void zero_rows(float* __restrict__ out) {
  int idx = blockIdx.x * 256 + threadIdx.x;   // 4096 total
  if (idx < 4096) out[(size_t)(idx >> 10) * (4097u * 1024u) + (idx & 1023)] = 0.f;
}

// ---------------- generic 128x128 bf16 MFMA GEMM ----------------------------
// MODE 0: A = seq rows f32 (+1 offset), B = wqT,  C -> qws bf16 (scaled 0.125)
// MODE 1: A = context f32 (127 left-pad zeros), B = wkvT, C -> kws/vws bf16
// MODE 2: A = ows bf16, B = woutT, C -> d_out f32 (+b_out) at row +1 per batch
template <int MODE>
__global__ __launch_bounds__(256, 2) void gemm_k(const void* __restrict__ Av,
                                                 const short* __restrict__ BT,
                                                 const float* __restrict__ bias,
                                                 void* __restrict__ C1v,
                                                 short* __restrict__ C2) {
  constexpr int Ksz = (MODE == 2) ? 512 : 1024;
  __shared__ short As[128 * 40];   // stride 40 (80B): 2-way bank alias (free), 16B aligned
  __shared__ short Bs[128 * 40];   // stored [n][k]
  const int t = threadIdx.x;
  const int bm = blockIdx.x, bn = blockIdx.y;
  const int wid = t >> 6, lane = t & 63, qd = lane >> 4, ln = lane & 15;
  const int wm = wid >> 1, wn = wid & 1;

  const f32x4 zf = {0.f, 0.f, 0.f, 0.f};
  f32x4 acc[4][4];
#pragma unroll
  for (int it = 0; it < 4; ++it)
#pragma unroll
    for (int jt = 0; jt < 4; ++jt) acc[it][jt] = zf;

  const int arow = t >> 1;              // 0..127
  const int koff = (t & 1) * 16;        // 0 / 16
  const float* asrcF = nullptr;
  const short* asrcB = nullptr;
  bool avalid = true;
  {
    int gr = bm * 128 + arow;
    if constexpr (MODE == 0) {
      int b = gr >> 12, i = gr & 4095;
      asrcF = (const float*)Av + ((size_t)b * 4097 + 1 + i) * 1024;
    } else if constexpr (MODE == 1) {
      int b = gr >> 13, j = gr & 8191;
      avalid = (j >= 127);
      asrcF = (const float*)Av + ((size_t)b * 8065 + (j - 127)) * 1024;
    } else {
      asrcB = (const short*)Av + (size_t)gr * 512;
    }
  }
  const short* bsrc = BT + (size_t)(bn * 128 + arow) * Ksz;

  for (int kt = 0; kt < Ksz / 32; ++kt) {
    const int k0 = kt * 32 + koff;
    bf16x8 a0, a1;
    if constexpr (MODE == 2) {
      a0 = *(const bf16x8*)(asrcB + k0);
      a1 = *(const bf16x8*)(asrcB + k0 + 8);
    } else {
      f32x4 f0 = zf, f1 = zf, f2 = zf, f3 = zf;
      if (avalid) {
        f0 = *(const f32x4*)(asrcF + k0);
        f1 = *(const f32x4*)(asrcF + k0 + 4);
        f2 = *(const f32x4*)(asrcF + k0 + 8);
        f3 = *(const f32x4*)(asrcF + k0 + 12);
      }
#pragma unroll
      for (int i = 0; i < 4; ++i) {
        a0[i]     = f2bf_r(f0[i]);
        a0[i + 4] = f2bf_r(f1[i]);
        a1[i]     = f2bf_r(f2[i]);
        a1[i + 4] = f2bf_r(f3[i]);
      }
    }
    bf16x8 b0 = *(const bf16x8*)(bsrc + k0);
    bf16x8 b1 = *(const bf16x8*)(bsrc + k0 + 8);
    *(bf16x8*)&As[arow * 40 + koff] = a0;
    *(bf16x8*)&As[arow * 40 + koff + 8] = a1;
    *(bf16x8*)&Bs[arow * 40 + koff] = b0;
    *(bf16x8*)&Bs[arow * 40 + koff + 8] = b1;
    __syncthreads();
    bf16x8 af[4], bfv[4];
#pragma unroll
    for (int it = 0; it < 4; ++it)
      af[it] = *(const bf16x8*)&As[(wm * 64 + it * 16 + ln) * 40 + qd * 8];
#pragma unroll
    for (int jt = 0; jt < 4; ++jt)
      bfv[jt] = *(const bf16x8*)&Bs[(wn * 64 + jt * 16 + ln) * 40 + qd * 8];
#pragma unroll
    for (int it = 0; it < 4; ++it)
#pragma unroll
      for (int jt = 0; jt < 4; ++jt)
        acc[it][jt] = __builtin_amdgcn_mfma_f32_16x16x32_bf16(af[it], bfv[jt], acc[it][jt], 0, 0, 0);
    __syncthreads();
  }

  // epilogue: C/D layout col=lane&15, row=(lane>>4)*4+reg  [m89/m91 verified]
#pragma unroll
  for (int it = 0; it < 4; ++it) {
    const int rbase = bm * 128 + wm * 64 + it * 16 + qd * 4;
#pragma unroll
    for (int jt = 0; jt < 4; ++jt) {
      const int cc = bn * 128 + wn * 64 + jt * 16 + ln;
      float bia = 0.f;
      if constexpr (MODE == 2) bia = bias[cc];
#pragma unroll
      for (int rr = 0; rr < 4; ++rr) {
        const int rg = rbase + rr;
        const float v = acc[it][jt][rr];
        if constexpr (MODE == 0) {
          int b = rg >> 12, i = rg & 4095;
          int nch = i >> 6, ic = i & 63;
          int h = cc >> 6, d = cc & 63;
          ((short*)C1v)[(((size_t)(b * 8 + h) * 64 + nch) * 64 + ic) * 64 + d] = f2bf(v * 0.125f);
        } else if constexpr (MODE == 1) {
          int b = rg >> 13, j = rg & 8191;
          int nch = j >> 7, jc = j & 127;
          int d = cc & 63;
          if (cc < 512) {
            int h = cc >> 6;
            ((short*)C1v)[(((size_t)(b * 8 + h) * 64 + nch) * 128 + jc) * 64 + d] = f2bf(v);
          } else {
            int h = (cc - 512) >> 6;
            C2[(((size_t)(b * 8 + h) * 64 + nch) * 128 + jc) * 64 + d] = f2bf(v);
          }
        } else {
          int b = rg >> 12, i = rg & 4095;
          ((float*)C1v)[((size_t)b * 4097 + 1 + i) * 1024 + cc] = v + bia;
        }
      }
    }
  }
}

// ---------------- fused attention (sim, softmax, talking-heads, PV) ---------
// grid: 1024 blocks = (b:4) x (nch:64) x (quarter:4 of 16 q-rows); 512 thr = 8 waves.
// wave = head. Columns: j 0..127 = context keys, j 128 = null key.
__global__ __launch_bounds__(512, 2) void attn_kernel(
    const short* __restrict__ qws, const short* __restrict__ kws,
    const short* __restrict__ vws, const float* __restrict__ null_k,
    const float* __restrict__ null_v, const float* __restrict__ W_th,
    const float* __restrict__ b_th, short* __restrict__ ows) {
  __shared__ short P[8 * 16 * 152];   // [head][row(16)][col stride 152]; 38 KB

  const int blk = blockIdx.x;
  const int b = blk >> 8;
  const int rem = blk & 255;
  const int nch = rem >> 2;
  const int qh = rem & 3;
  const int tid = threadIdx.x;
  const int wid = tid >> 6;            // head (phase1) / out-head g (phase3)
  const int lane = tid & 63;
  const int qd = lane >> 4, ln = lane & 15;

  const bf16x8 z8 = {0, 0, 0, 0, 0, 0, 0, 0};
  const f32x4 zf = {0.f, 0.f, 0.f, 0.f};

  // ---- phase 1: sim = q k^T for head wid -----------------------------------
  const short* qb = qws + ((size_t)(b * 8 + wid) * 64 + nch) * 64 * 64;
  const short* kb = kws + ((size_t)(b * 8 + wid) * 64 + nch) * 128 * 64;

  bf16x8 qf[2];
#pragma unroll
  for (int kk = 0; kk < 2; ++kk)
    qf[kk] = *(const bf16x8*)(qb + (qh * 16 + ln) * 64 + kk * 32 + qd * 8);

  f32x4 acc[9];
#pragma unroll
  for (int jt = 0; jt < 9; ++jt) acc[jt] = zf;

#pragma unroll
  for (int jt = 0; jt < 8; ++jt) {
#pragma unroll
    for (int kk = 0; kk < 2; ++kk) {
      bf16x8 bfr = *(const bf16x8*)(kb + (jt * 16 + ln) * 64 + kk * 32 + qd * 8);
      acc[jt] = __builtin_amdgcn_mfma_f32_16x16x32_bf16(qf[kk], bfr, acc[jt], 0, 0, 0);
    }
  }
  {  // null-key column (col 128): only lane col 0 carries data
#pragma unroll
    for (int kk = 0; kk < 2; ++kk) {
      bf16x8 nk = z8;
      if (ln == 0) {
#pragma unroll
        for (int j = 0; j < 8; ++j)
          nk[j] = f2bf(null_k[wid * 64 + kk * 32 + qd * 8 + j]);
      }
      acc[8] = __builtin_amdgcn_mfma_f32_16x16x32_bf16(qf[kk], nk, acc[8], 0, 0, 0);
    }
  }

  // ---- softmax over 129 cols (rows = qd*4+rr), write P bf16 to LDS ---------
#pragma unroll
  for (int rr = 0; rr < 4; ++rr) {
    float v[9];
    float m = -3.0e38f;
#pragma unroll
    for (int jt = 0; jt < 9; ++jt) {
      float x = acc[jt][rr];
      if (jt == 8 && ln != 0) x = -3.0e38f;
      v[jt] = x;
      m = fmaxf(m, x);
    }
#pragma unroll
    for (int s = 1; s < 16; s <<= 1) m = fmaxf(m, __shfl_xor(m, s, 64));
    float sum = 0.f;
#pragma unroll
    for (int jt = 0; jt < 9; ++jt) {
      float e = (jt == 8 && ln != 0) ? 0.f : exp2f((v[jt] - m) * 1.44269504f);
      v[jt] = e;
      sum += e;
    }
#pragma unroll
    for (int s = 1; s < 16; s <<= 1) sum += __shfl_xor(sum, s, 64);
    const float inv = 1.0f / sum;
    const int row = qd * 4 + rr;
#pragma unroll
    for (int jt = 0; jt < 9; ++jt)
      P[(wid * 16 + row) * 152 + jt * 16 + ln] = f2bf(v[jt] * inv);
  }
  __syncthreads();

  // ---- talking-heads mix, in place (each (r,c) owned by one thread) --------
  {
    float w[64];
#pragma unroll
    for (int i = 0; i < 64; ++i) {
      union { float f; int i; } u;
      u.f = W_th[i];
      u.i = __builtin_amdgcn_readfirstlane(u.i);
      w[i] = u.f;
    }
    float bt[8];
#pragma unroll
    for (int g = 0; g < 8; ++g) {
      union { float f; int i; } u;
      u.f = b_th[g];
      u.i = __builtin_amdgcn_readfirstlane(u.i);
      bt[g] = u.f;
    }
    const int r = tid >> 5;           // 0..15
    const int c0 = (tid & 31) * 5;    // 5 cols per thread, cols 0..128
    for (int c = c0; c < c0 + 5 && c < 129; ++c) {
      float v[8];
#pragma unroll
      for (int h = 0; h < 8; ++h) v[h] = bf2f(P[(h * 16 + r) * 152 + c]);
      float o[8];
#pragma unroll
      for (int g = 0; g < 8; ++g) {
        float s = bt[g];
#pragma unroll
        for (int h = 0; h < 8; ++h) s += w[g * 8 + h] * v[h];
        o[g] = s;
      }
#pragma unroll
      for (int g = 0; g < 8; ++g) P[(g * 16 + r) * 152 + c] = f2bf(o[g]);
    }
  }
  __syncthreads();

  // ---- phase 3: O = P' @ V for out-head g = wid ----------------------------
  const short* vb = vws + ((size_t)(b * 8 + wid) * 64 + nch) * 128 * 64;
  bf16x8 vf[4][4];
#pragma unroll
  for (int kk = 0; kk < 4; ++kk)
#pragma unroll
    for (int dt = 0; dt < 4; ++dt) {
      bf16x8 tmp;
#pragma unroll
      for (int jj = 0; jj < 8; ++jj)
        tmp[jj] = vb[(kk * 32 + qd * 8 + jj) * 64 + dt * 16 + ln];
      vf[kk][dt] = tmp;
    }

  f32x4 oacc[4];
#pragma unroll
  for (int dt = 0; dt < 4; ++dt) oacc[dt] = zf;

#pragma unroll
  for (int kk = 0; kk < 4; ++kk) {
    bf16x8 af = *(const bf16x8*)&P[(wid * 16 + ln) * 152 + kk * 32 + qd * 8];
#pragma unroll
    for (int dt = 0; dt < 4; ++dt)
      oacc[dt] = __builtin_amdgcn_mfma_f32_16x16x32_bf16(af, vf[kk][dt], oacc[dt], 0, 0, 0);
  }
  // rank-1 update for null-value column (col 128)
  {
    float nv[4];
#pragma unroll
    for (int dt = 0; dt < 4; ++dt) nv[dt] = null_v[wid * 64 + dt * 16 + ln];
#pragma unroll
    for (int rr = 0; rr < 4; ++rr) {
      float p = bf2f(P[(wid * 16 + qd * 4 + rr) * 152 + 128]);
#pragma unroll
      for (int dt = 0; dt < 4; ++dt) oacc[dt][rr] += p * nv[dt];
    }
  }
  // write O: [16384][512] bf16
  const size_t rowbase = (size_t)b * 4096 + nch * 64 + qh * 16;
#pragma unroll
  for (int dt = 0; dt < 4; ++dt)
#pragma unroll
    for (int rr = 0; rr < 4; ++rr)
      ows[(rowbase + qd * 4 + rr) * 512 + wid * 64 + dt * 16 + ln] = f2bf(oacc[dt][rr]);
}

// ---------------------------------------------------------------------------
extern "C" void kernel_launch(void* const* d_in, const int* in_sizes, int n_in,
                              void* d_out, int out_size, void* d_ws, size_t ws_size,
                              hipStream_t stream) {
  const float* seq   = (const float*)d_in[0];
  const float* ctx   = (const float*)d_in[1];
  const float* Wq    = (const float*)d_in[2];
  const float* Wkv   = (const float*)d_in[3];
  const float* Wout  = (const float*)d_in[4];
  const float* b_out = (const float*)d_in[5];
  const float* nullk = (const float*)d_in[6];
  const float* nullv = (const float*)d_in[7];
  const float* W_th  = (const float*)d_in[8];
  const float* b_th  = (const float*)d_in[9];

  char* ws = (char*)d_ws;
  short* qws   = (short*)(ws);
  short* kws   = (short*)(ws + 16777216);
  short* vws   = (short*)(ws + 50331648);
  short* ows   = (short*)(ws + 83886080);
  short* wqT   = (short*)(ws + 100663296);
  short* wkvT  = (short*)(ws + 101711872);
  short* woutT = (short*)(ws + 103809024);
  float* out   = (float*)d_out;

  hipLaunchKernelGGL(transpose_w, dim3(8192), dim3(256), 0, stream,
                     Wq, Wkv, Wout, wqT, wkvT, woutT);
  hipLaunchKernelGGL((gemm_k<0>), dim3(128, 4), dim3(256), 0, stream,
                     (const void*)seq, wqT, (const float*)nullptr, (void*)qws, (short*)nullptr);
  hipLaunchKernelGGL((gemm_k<1>), dim3(256, 8), dim3(256), 0, stream,
                     (const void*)ctx, wkvT, (const float*)nullptr, (void*)kws, vws);
  hipLaunchKernelGGL(attn_kernel, dim3(1024), dim3(512), 0, stream,
                     qws, kws, vws, nullk, nullv, W_th, b_th, ows);
  hipLaunchKernelGGL(zero_rows, dim3(16), dim3(256), 0, stream, out);
  hipLaunchKernelGGL((gemm_k<2>), dim3(128, 8), dim3(256), 0, stream,
                     (const void*)ows, woutT, b_out, (void*)out, (short*)nullptr);
}

// Round 4
// 514.150 us; speedup vs baseline: 1.0120x; 1.0120x over previous
//
#include <hip/hip_runtime.h>

// ---------------------------------------------------------------------------
// CrossModalityCrossAttention on MI355X (gfx950). I/O: float32. Internal: bf16.
// B=4 S=4097 L=8065 D=1024 H=8 DH=64 CHUNK=64 CCS=128 n=64 chunks.
//
// FAST path (ws_size >= 180 MB): pre-convert seq/ctx to bf16, then m97-style
//   GEMMs with global_load_lds width=16 (no staging VGPRs / no per-iter cvt).
// FALLBACK path (smaller ws): round-3 known-good f32-staging GEMMs.
//
// Fast ws layout (bytes), total 188,743,680:
//   seqb  @ 0          : [16384][1024] bf16 (33.5 MB)   seq rows 1..4096/batch
//   ows   @ 0          : [16384][512]  bf16 (16.8 MB)   (reuses seqb after Q GEMM)
//   ctxb  @ 33554432   : [4][8192][1024] bf16 (67.1 MB) 127-row left-pad built in
//   qws   @ 100663296  : [b][h][n][64][64]  bf16 (16.8 MB)  q * 0.125
//   kws   @ 117440512  : [b][h][n][128][64] bf16 (33.5 MB)
//   vws   @ 150994944  : [b][h][n][128][64] bf16 (33.5 MB)
//   wqT   @ 184549376  : [512][1024]  bf16
//   wkvT  @ 185597952  : [1024][1024] bf16
//   woutT @ 187695104  : [1024][512]  bf16
// ---------------------------------------------------------------------------

typedef __attribute__((ext_vector_type(8))) short bf16x8;
typedef __attribute__((ext_vector_type(4))) float f32x4;

__device__ __forceinline__ short f2bf(float x) {        // RNE (epilogues, weights)
  union { float f; unsigned u; } v; v.f = x;
  unsigned r = v.u + 0x7FFFu + ((v.u >> 16) & 1u);
  return (short)(r >> 16);
}
__device__ __forceinline__ short f2bf_r(float x) {      // round-half-up (staging)
  union { float f; unsigned u; } v; v.f = x;
  return (short)((v.u + 0x8000u) >> 16);
}
__device__ __forceinline__ float bf2f(short s) {
  union { unsigned u; float f; } v;
  v.u = ((unsigned)(unsigned short)s) << 16;
  return v.f;
}
__device__ __forceinline__ void glds16(const short* g, short* l) {
  __builtin_amdgcn_global_load_lds(
      (const __attribute__((address_space(1))) void*)g,
      (__attribute__((address_space(3))) void*)l, 16, 0, 0);
}

// ---------------- weight transpose (f32 [k][n] -> bf16 [n][k]) --------------
__global__ void transpose_w(const float* __restrict__ Wq, const float* __restrict__ Wkv,
                            const float* __restrict__ Wout,
                            short* __restrict__ wqT, short* __restrict__ wkvT,
                            short* __restrict__ woutT) {
  int idx = blockIdx.x * 256 + threadIdx.x;
  if (idx < 524288) {                       // Wq (1024 x 512)
    int d = idx >> 9, e = idx & 511;
    wqT[e * 1024 + d] = f2bf(Wq[idx]);
  } else if (idx < 1572864) {               // Wkv (1024 x 1024)
    int i = idx - 524288;
    int d = i >> 10, e = i & 1023;
    wkvT[e * 1024 + d] = f2bf(Wkv[i]);
  } else if (idx < 2097152) {               // Wout (512 x 1024)
    int i = idx - 1572864;
    int k = i >> 10, e = i & 1023;
    woutT[e * 512 + k] = f2bf(Wout[i]);
  }
}

// ---------------- f32 -> bf16 conversion passes (fast path) -----------------
__global__ void conv_seq(const float* __restrict__ seq, short* __restrict__ seqb) {
  size_t e = ((size_t)blockIdx.x * 256 + threadIdx.x) * 8;   // 16,777,216 elems
  int b = (int)(e >> 22);
  int i = (int)((e >> 10) & 4095);
  int k = (int)(e & 1023);
  const float* src = seq + ((size_t)b * 4097 + 1 + i) * 1024 + k;
  f32x4 f0 = *(const f32x4*)src;
  f32x4 f1 = *(const f32x4*)(src + 4);
  bf16x8 o;
#pragma unroll
  for (int j = 0; j < 4; ++j) { o[j] = f2bf_r(f0[j]); o[j + 4] = f2bf_r(f1[j]); }
  *(bf16x8*)(seqb + e) = o;
}

__global__ void conv_ctx(const float* __restrict__ ctx, short* __restrict__ ctxb) {
  size_t e = ((size_t)blockIdx.x * 256 + threadIdx.x) * 8;   // 33,554,432 elems
  int b = (int)(e >> 23);
  int r = (int)((e >> 10) & 8191);
  int k = (int)(e & 1023);
  bf16x8 o = {0, 0, 0, 0, 0, 0, 0, 0};
  if (r >= 127) {                            // rows 0..126 are the left pad
    const float* src = ctx + ((size_t)b * 8065 + (r - 127)) * 1024 + k;
    f32x4 f0 = *(const f32x4*)src;
    f32x4 f1 = *(const f32x4*)(src + 4);
#pragma unroll
    for (int j = 0; j < 4; ++j) { o[j] = f2bf_r(f0[j]); o[j + 4] = f2bf_r(f1[j]); }
  }
  *(bf16x8*)(ctxb + e) = o;
}

// ---------------- zero the (b, 0, :) output rows (f32) ----------------------
__global__ void zero_rows(float* __restrict__ out) {
  int idx = blockIdx.x * 256 + threadIdx.x;   // 4096 total
  if (idx < 4096) out[(size_t)(idx >> 10) * (4097u * 1024u) + (idx & 1023)] = 0.f;
}

// ---------------- FAST GEMM: 128x128 tile, global_load_lds staging ----------
// MODE 0: A = seqb, B = wqT,  C -> qws bf16 (scaled 0.125).  grid (128,4)
// MODE 1: A = ctxb (pre-padded), B = wkvT, C -> kws/vws.     grid (256,8)
// MODE 2: A = ows,  B = woutT, C -> d_out f32 (+b_out).      grid (128,8)
template <int MODE>
__global__ __launch_bounds__(256, 2) void gemm_fast(const short* __restrict__ A,
                                                    const short* __restrict__ BT,
                                                    const float* __restrict__ bias,
                                                    void* __restrict__ C1v,
                                                    short* __restrict__ C2) {
  constexpr int Ksz = (MODE == 2) ? 512 : 1024;
  __shared__ short As[128 * 32];   // unpadded: required by global_load_lds layout
  __shared__ short Bs[128 * 32];
  const int t = threadIdx.x;
  const int bm = blockIdx.x, bn = blockIdx.y;
  const int wid = t >> 6, lane = t & 63, qd = lane >> 4, ln = lane & 15;
  const int wm = wid >> 1, wn = wid & 1;

  const f32x4 zf = {0.f, 0.f, 0.f, 0.f};
  f32x4 acc[4][4];
#pragma unroll
  for (int it = 0; it < 4; ++it)
#pragma unroll
    for (int jt = 0; jt < 4; ++jt) acc[it][jt] = zf;

  // staging: lane l of wave w stages 16B at LDS (w*16 + l/4)*64B + (l%4)*16B
  //        = wave base (w*1024B) + l*16B  -> matches HW wave-uniform+lane*16.
  const int srow = wid * 16 + (lane >> 2);         // 0..63
  const int scol = (lane & 3) * 8;                 // shorts
  const short* aA0 = A + ((size_t)bm * 128 + srow) * Ksz + scol;
  const short* aA1 = aA0 + (size_t)64 * Ksz;
  const short* aB0 = BT + ((size_t)bn * 128 + srow) * Ksz + scol;
  const short* aB1 = aB0 + (size_t)64 * Ksz;
  short* lA0 = &As[srow * 32 + scol];
  short* lA1 = &As[(64 + srow) * 32 + scol];
  short* lB0 = &Bs[srow * 32 + scol];
  short* lB1 = &Bs[(64 + srow) * 32 + scol];

  for (int kt = 0; kt < Ksz / 32; ++kt) {
    const int ko = kt * 32;
    glds16(aA0 + ko, lA0);
    glds16(aA1 + ko, lA1);
    glds16(aB0 + ko, lB0);
    glds16(aB1 + ko, lB1);
    __syncthreads();
    bf16x8 af[4], bfv[4];
#pragma unroll
    for (int it = 0; it < 4; ++it)
      af[it] = *(const bf16x8*)&As[(wm * 64 + it * 16 + ln) * 32 + qd * 8];
#pragma unroll
    for (int jt = 0; jt < 4; ++jt)
      bfv[jt] = *(const bf16x8*)&Bs[(wn * 64 + jt * 16 + ln) * 32 + qd * 8];
#pragma unroll
    for (int it = 0; it < 4; ++it)
#pragma unroll
      for (int jt = 0; jt < 4; ++jt)
        acc[it][jt] = __builtin_amdgcn_mfma_f32_16x16x32_bf16(af[it], bfv[jt], acc[it][jt], 0, 0, 0);
    __syncthreads();
  }

  // epilogue: C/D layout col=lane&15, row=(lane>>4)*4+reg
#pragma unroll
  for (int it = 0; it < 4; ++it) {
    const int rbase = bm * 128 + wm * 64 + it * 16 + qd * 4;
#pragma unroll
    for (int jt = 0; jt < 4; ++jt) {
      const int cc = bn * 128 + wn * 64 + jt * 16 + ln;
      float bia = 0.f;
      if constexpr (MODE == 2) bia = bias[cc];
#pragma unroll
      for (int rr = 0; rr < 4; ++rr) {
        const int rg = rbase + rr;
        const float v = acc[it][jt][rr];
        if constexpr (MODE == 0) {
          int b = rg >> 12, i = rg & 4095;
          int nch = i >> 6, ic = i & 63;
          int h = cc >> 6, d = cc & 63;
          ((short*)C1v)[(((size_t)(b * 8 + h) * 64 + nch) * 64 + ic) * 64 + d] = f2bf(v * 0.125f);
        } else if constexpr (MODE == 1) {
          int b = rg >> 13, j = rg & 8191;     // j = padded ctx row
          int nch = j >> 7, jc = j & 127;
          int d = cc & 63;
          if (cc < 512) {
            int h = cc >> 6;
            ((short*)C1v)[(((size_t)(b * 8 + h) * 64 + nch) * 128 + jc) * 64 + d] = f2bf(v);
          } else {
            int h = (cc - 512) >> 6;
            C2[(((size_t)(b * 8 + h) * 64 + nch) * 128 + jc) * 64 + d] = f2bf(v);
          }
        } else {
          int b = rg >> 12, i = rg & 4095;
          ((float*)C1v)[((size_t)b * 4097 + 1 + i) * 1024 + cc] = v + bia;
        }
      }
    }
  }
}

// ---------------- FALLBACK GEMM (round-3, f32 A staging) --------------------
template <int MODE>
__global__ __launch_bounds__(256, 2) void gemm_k(const void* __restrict__ Av,
                                                 const short* __restrict__ BT,
                                                 const float* __restrict__ bias,
                                                 void* __restrict__ C1v,
                                                 short* __restrict__ C2) {
  constexpr int Ksz = (MODE == 2) ? 512 : 1024;
  __shared__ short As[128 * 40];
  __shared__ short Bs[128 * 40];
  const int t = threadIdx.x;
  const int bm = blockIdx.x, bn = blockIdx.y;
  const int wid = t >> 6, lane = t & 63, qd = lane >> 4, ln = lane & 15;
  const int wm = wid >> 1, wn = wid & 1;

  const f32x4 zf = {0.f, 0.f, 0.f, 0.f};
  f32x4 acc[4][4];
#pragma unroll
  for (int it = 0; it < 4; ++it)
#pragma unroll
    for (int jt = 0; jt < 4; ++jt) acc[it][jt] = zf;

  const int arow = t >> 1;
  const int koff = (t & 1) * 16;
  const float* asrcF = nullptr;
  const short* asrcB = nullptr;
  bool avalid = true;
  {
    int gr = bm * 128 + arow;
    if constexpr (MODE == 0) {
      int b = gr >> 12, i = gr & 4095;
      asrcF = (const float*)Av + ((size_t)b * 4097 + 1 + i) * 1024;
    } else if constexpr (MODE == 1) {
      int b = gr >> 13, j = gr & 8191;
      avalid = (j >= 127);
      asrcF = (const float*)Av + ((size_t)b * 8065 + (j - 127)) * 1024;
    } else {
      asrcB = (const short*)Av + (size_t)gr * 512;
    }
  }
  const short* bsrc = BT + (size_t)(bn * 128 + arow) * Ksz;

  for (int kt = 0; kt < Ksz / 32; ++kt) {
    const int k0 = kt * 32 + koff;
    bf16x8 a0, a1;
    if constexpr (MODE == 2) {
      a0 = *(const bf16x8*)(asrcB + k0);
      a1 = *(const bf16x8*)(asrcB + k0 + 8);
    } else {
      f32x4 f0 = zf, f1 = zf, f2 = zf, f3 = zf;
      if (avalid) {
        f0 = *(const f32x4*)(asrcF + k0);
        f1 = *(const f32x4*)(asrcF + k0 + 4);
        f2 = *(const f32x4*)(asrcF + k0 + 8);
        f3 = *(const f32x4*)(asrcF + k0 + 12);
      }
#pragma unroll
      for (int i = 0; i < 4; ++i) {
        a0[i]     = f2bf_r(f0[i]);
        a0[i + 4] = f2bf_r(f1[i]);
        a1[i]     = f2bf_r(f2[i]);
        a1[i + 4] = f2bf_r(f3[i]);
      }
    }
    bf16x8 b0 = *(const bf16x8*)(bsrc + k0);
    bf16x8 b1 = *(const bf16x8*)(bsrc + k0 + 8);
    *(bf16x8*)&As[arow * 40 + koff] = a0;
    *(bf16x8*)&As[arow * 40 + koff + 8] = a1;
    *(bf16x8*)&Bs[arow * 40 + koff] = b0;
    *(bf16x8*)&Bs[arow * 40 + koff + 8] = b1;
    __syncthreads();
    bf16x8 af[4], bfv[4];
#pragma unroll
    for (int it = 0; it < 4; ++it)
      af[it] = *(const bf16x8*)&As[(wm * 64 + it * 16 + ln) * 40 + qd * 8];
#pragma unroll
    for (int jt = 0; jt < 4; ++jt)
      bfv[jt] = *(const bf16x8*)&Bs[(wn * 64 + jt * 16 + ln) * 40 + qd * 8];
#pragma unroll
    for (int it = 0; it < 4; ++it)
#pragma unroll
      for (int jt = 0; jt < 4; ++jt)
        acc[it][jt] = __builtin_amdgcn_mfma_f32_16x16x32_bf16(af[it], bfv[jt], acc[it][jt], 0, 0, 0);
    __syncthreads();
  }

#pragma unroll
  for (int it = 0; it < 4; ++it) {
    const int rbase = bm * 128 + wm * 64 + it * 16 + qd * 4;
#pragma unroll
    for (int jt = 0; jt < 4; ++jt) {
      const int cc = bn * 128 + wn * 64 + jt * 16 + ln;
      float bia = 0.f;
      if constexpr (MODE == 2) bia = bias[cc];
#pragma unroll
      for (int rr = 0; rr < 4; ++rr) {
        const int rg = rbase + rr;
        const float v = acc[it][jt][rr];
        if constexpr (MODE == 0) {
          int b = rg >> 12, i = rg & 4095;
          int nch = i >> 6, ic = i & 63;
          int h = cc >> 6, d = cc & 63;
          ((short*)C1v)[(((size_t)(b * 8 + h) * 64 + nch) * 64 + ic) * 64 + d] = f2bf(v * 0.125f);
        } else if constexpr (MODE == 1) {
          int b = rg >> 13, j = rg & 8191;
          int nch = j >> 7, jc = j & 127;
          int d = cc & 63;
          if (cc < 512) {
            int h = cc >> 6;
            ((short*)C1v)[(((size_t)(b * 8 + h) * 64 + nch) * 128 + jc) * 64 + d] = f2bf(v);
          } else {
            int h = (cc - 512) >> 6;
            C2[(((size_t)(b * 8 + h) * 64 + nch) * 128 + jc) * 64 + d] = f2bf(v);
          }
        } else {
          int b = rg >> 12, i = rg & 4095;
          ((float*)C1v)[((size_t)b * 4097 + 1 + i) * 1024 + cc] = v + bia;
        }
      }
    }
  }
}

// ---------------- fused attention (sim, softmax, talking-heads, PV) ---------
__global__ __launch_bounds__(512, 2) void attn_kernel(
    const short* __restrict__ qws, const short* __restrict__ kws,
    const short* __restrict__ vws, const float* __restrict__ null_k,
    const float* __restrict__ null_v, const float* __restrict__ W_th,
    const float* __restrict__ b_th, short* __restrict__ ows) {
  __shared__ short P[8 * 16 * 152];

  const int blk = blockIdx.x;
  const int b = blk >> 8;
  const int rem = blk & 255;
  const int nch = rem >> 2;
  const int qh = rem & 3;
  const int tid = threadIdx.x;
  const int wid = tid >> 6;
  const int lane = tid & 63;
  const int qd = lane >> 4, ln = lane & 15;

  const bf16x8 z8 = {0, 0, 0, 0, 0, 0, 0, 0};
  const f32x4 zf = {0.f, 0.f, 0.f, 0.f};

  const short* qb = qws + ((size_t)(b * 8 + wid) * 64 + nch) * 64 * 64;
  const short* kb = kws + ((size_t)(b * 8 + wid) * 64 + nch) * 128 * 64;

  bf16x8 qf[2];
#pragma unroll
  for (int kk = 0; kk < 2; ++kk)
    qf[kk] = *(const bf16x8*)(qb + (qh * 16 + ln) * 64 + kk * 32 + qd * 8);

  f32x4 acc[9];
#pragma unroll
  for (int jt = 0; jt < 9; ++jt) acc[jt] = zf;

#pragma unroll
  for (int jt = 0; jt < 8; ++jt) {
#pragma unroll
    for (int kk = 0; kk < 2; ++kk) {
      bf16x8 bfr = *(const bf16x8*)(kb + (jt * 16 + ln) * 64 + kk * 32 + qd * 8);
      acc[jt] = __builtin_amdgcn_mfma_f32_16x16x32_bf16(qf[kk], bfr, acc[jt], 0, 0, 0);
    }
  }
  {
#pragma unroll
    for (int kk = 0; kk < 2; ++kk) {
      bf16x8 nk = z8;
      if (ln == 0) {
#pragma unroll
        for (int j = 0; j < 8; ++j)
          nk[j] = f2bf(null_k[wid * 64 + kk * 32 + qd * 8 + j]);
      }
      acc[8] = __builtin_amdgcn_mfma_f32_16x16x32_bf16(qf[kk], nk, acc[8], 0, 0, 0);
    }
  }

#pragma unroll
  for (int rr = 0; rr < 4; ++rr) {
    float v[9];
    float m = -3.0e38f;
#pragma unroll
    for (int jt = 0; jt < 9; ++jt) {
      float x = acc[jt][rr];
      if (jt == 8 && ln != 0) x = -3.0e38f;
      v[jt] = x;
      m = fmaxf(m, x);
    }
#pragma unroll
    for (int s = 1; s < 16; s <<= 1) m = fmaxf(m, __shfl_xor(m, s, 64));
    float sum = 0.f;
#pragma unroll
    for (int jt = 0; jt < 9; ++jt) {
      float e = (jt == 8 && ln != 0) ? 0.f : exp2f((v[jt] - m) * 1.44269504f);
      v[jt] = e;
      sum += e;
    }
#pragma unroll
    for (int s = 1; s < 16; s <<= 1) sum += __shfl_xor(sum, s, 64);
    const float inv = 1.0f / sum;
    const int row = qd * 4 + rr;
#pragma unroll
    for (int jt = 0; jt < 9; ++jt)
      P[(wid * 16 + row) * 152 + jt * 16 + ln] = f2bf(v[jt] * inv);
  }
  __syncthreads();

  {
    float w[64];
#pragma unroll
    for (int i = 0; i < 64; ++i) {
      union { float f; int i; } u;
      u.f = W_th[i];
      u.i = __builtin_amdgcn_readfirstlane(u.i);
      w[i] = u.f;
    }
    float bt[8];
#pragma unroll
    for (int g = 0; g < 8; ++g) {
      union { float f; int i; } u;
      u.f = b_th[g];
      u.i = __builtin_amdgcn_readfirstlane(u.i);
      bt[g] = u.f;
    }
    const int r = tid >> 5;
    const int c0 = (tid & 31) * 5;
    for (int c = c0; c < c0 + 5 && c < 129; ++c) {
      float v[8];
#pragma unroll
      for (int h = 0; h < 8; ++h) v[h] = bf2f(P[(h * 16 + r) * 152 + c]);
      float o[8];
#pragma unroll
      for (int g = 0; g < 8; ++g) {
        float s = bt[g];
#pragma unroll
        for (int h = 0; h < 8; ++h) s += w[g * 8 + h] * v[h];
        o[g] = s;
      }
#pragma unroll
      for (int g = 0; g < 8; ++g) P[(g * 16 + r) * 152 + c] = f2bf(o[g]);
    }
  }
  __syncthreads();

  const short* vb = vws + ((size_t)(b * 8 + wid) * 64 + nch) * 128 * 64;
  bf16x8 vf[4][4];
#pragma unroll
  for (int kk = 0; kk < 4; ++kk)
#pragma unroll
    for (int dt = 0; dt < 4; ++dt) {
      bf16x8 tmp;
#pragma unroll
      for (int jj = 0; jj < 8; ++jj)
        tmp[jj] = vb[(kk * 32 + qd * 8 + jj) * 64 + dt * 16 + ln];
      vf[kk][dt] = tmp;
    }

  f32x4 oacc[4];
#pragma unroll
  for (int dt = 0; dt < 4; ++dt) oacc[dt] = zf;

#pragma unroll
  for (int kk = 0; kk < 4; ++kk) {
    bf16x8 af = *(const bf16x8*)&P[(wid * 16 + ln) * 152 + kk * 32 + qd * 8];
#pragma unroll
    for (int dt = 0; dt < 4; ++dt)
      oacc[dt] = __builtin_amdgcn_mfma_f32_16x16x32_bf16(af, vf[kk][dt], oacc[dt], 0, 0, 0);
  }
  {
    float nv[4];
#pragma unroll
    for (int dt = 0; dt < 4; ++dt) nv[dt] = null_v[wid * 64 + dt * 16 + ln];
#pragma unroll
    for (int rr = 0; rr < 4; ++rr) {
      float p = bf2f(P[(wid * 16 + qd * 4 + rr) * 152 + 128]);
#pragma unroll
      for (int dt = 0; dt < 4; ++dt) oacc[dt][rr] += p * nv[dt];
    }
  }
  const size_t rowbase = (size_t)b * 4096 + nch * 64 + qh * 16;
#pragma unroll
  for (int dt = 0; dt < 4; ++dt)
#pragma unroll
    for (int rr = 0; rr < 4; ++rr)
      ows[(rowbase + qd * 4 + rr) * 512 + wid * 64 + dt * 16 + ln] = f2bf(oacc[dt][rr]);
}

// ---------------------------------------------------------------------------
extern "C" void kernel_launch(void* const* d_in, const int* in_sizes, int n_in,
                              void* d_out, int out_size, void* d_ws, size_t ws_size,
                              hipStream_t stream) {
  const float* seq   = (const float*)d_in[0];
  const float* ctx   = (const float*)d_in[1];
  const float* Wq    = (const float*)d_in[2];
  const float* Wkv   = (const float*)d_in[3];
  const float* Wout  = (const float*)d_in[4];
  const float* b_out = (const float*)d_in[5];
  const float* nullk = (const float*)d_in[6];
  const float* nullv = (const float*)d_in[7];
  const float* W_th  = (const float*)d_in[8];
  const float* b_th  = (const float*)d_in[9];

  char* ws = (char*)d_ws;
  float* out = (float*)d_out;
  const bool fast = ws_size >= 188743680ull;

  if (fast) {
    short* seqb  = (short*)(ws);
    short* ows   = (short*)(ws);                 // reuses seqb after Q GEMM
    short* ctxb  = (short*)(ws + 33554432);
    short* qws   = (short*)(ws + 100663296);
    short* kws   = (short*)(ws + 117440512);
    short* vws   = (short*)(ws + 150994944);
    short* wqT   = (short*)(ws + 184549376);
    short* wkvT  = (short*)(ws + 185597952);
    short* woutT = (short*)(ws + 187695104);

    hipLaunchKernelGGL(transpose_w, dim3(8192), dim3(256), 0, stream,
                       Wq, Wkv, Wout, wqT, wkvT, woutT);
    hipLaunchKernelGGL(conv_seq, dim3(8192), dim3(256), 0, stream, seq, seqb);
    hipLaunchKernelGGL(conv_ctx, dim3(16384), dim3(256), 0, stream, ctx, ctxb);
    hipLaunchKernelGGL((gemm_fast<0>), dim3(128, 4), dim3(256), 0, stream,
                       seqb, wqT, (const float*)nullptr, (void*)qws, (short*)nullptr);
    hipLaunchKernelGGL((gemm_fast<1>), dim3(256, 8), dim3(256), 0, stream,
                       ctxb, wkvT, (const float*)nullptr, (void*)kws, vws);
    hipLaunchKernelGGL(attn_kernel, dim3(1024), dim3(512), 0, stream,
                       qws, kws, vws, nullk, nullv, W_th, b_th, ows);
    hipLaunchKernelGGL(zero_rows, dim3(16), dim3(256), 0, stream, out);
    hipLaunchKernelGGL((gemm_fast<2>), dim3(128, 8), dim3(256), 0, stream,
                       ows, woutT, b_out, (void*)out, (short*)nullptr);
  } else {
    short* qws   = (short*)(ws);
    short* kws   = (short*)(ws + 16777216);
    short* vws   = (short*)(ws + 50331648);
    short* ows   = (short*)(ws + 83886080);
    short* wqT   = (short*)(ws + 100663296);
    short* wkvT  = (short*)(ws + 101711872);
    short* woutT = (short*)(ws + 103809024);

    hipLaunchKernelGGL(transpose_w, dim3(8192), dim3(256), 0, stream,
                       Wq, Wkv, Wout, wqT, wkvT, woutT);
    hipLaunchKernelGGL((gemm_k<0>), dim3(128, 4), dim3(256), 0, stream,
                       (const void*)seq, wqT, (const float*)nullptr, (void*)qws, (short*)nullptr);
    hipLaunchKernelGGL((gemm_k<1>), dim3(256, 8), dim3(256), 0, stream,
                       (const void*)ctx, wkvT, (const float*)nullptr, (void*)kws, vws);
    hipLaunchKernelGGL(attn_kernel, dim3(1024), dim3(512), 0, stream,
                       qws, kws, vws, nullk, nullv, W_th, b_th, ows);
    hipLaunchKernelGGL(zero_rows, dim3(16), dim3(256), 0, stream, out);
    hipLaunchKernelGGL((gemm_k<2>), dim3(128, 8), dim3(256), 0, stream,
                       (const void*)ows, woutT, b_out, (void*)out, (short*)nullptr);
  }
}